// Round 1
// baseline (5006.086 us; speedup 1.0000x reference)
//
#include <hip/hip_runtime.h>

#define B_ 2048
#define T_ 48
#define V_ 59
#define H_ 512
#define KP_ 640   // padded K for gates GEMM (59+59+512+10)
#define G4_ 2048  // 4*H
#define NBLK_ 256

typedef __bf16 bf16x8 __attribute__((ext_vector_type(8)));
typedef float f32x4 __attribute__((ext_vector_type(4)));

__device__ __forceinline__ unsigned short f2bf(float x){
  union { float f; unsigned u; } v; v.f = x;
  unsigned r = (v.u + 0x7FFFu + ((v.u >> 16) & 1u)) >> 16;
  return (unsigned short)r;
}
__device__ __forceinline__ float sigf(float x){ return 1.f/(1.f+expf(-x)); }

// ---- workspace layout (bytes) ----
static const size_t OFF_H    = 0;                          // h fp32 [2048*512] = 4 MB
static const size_t OFF_LN   = 4194304;                    // loss_num[48]
static const size_t OFF_LD   = OFF_LN + 256;               // loss_den[48]
static const size_t OFF_CNT  = OFF_LD + 256;               // grid-barrier counter
static const size_t MEMSET_BYTES = OFF_CNT + 256;
static const size_t OFF_A    = MEMSET_BYTES;               // A bf16 [2048*640]
static const size_t OFF_WGT  = OFF_A + (size_t)B_*KP_*2;   // WgT bf16 [2048*640]
static const size_t OFF_WGH  = OFF_WGT + (size_t)G4_*KP_*2;// WghT f32 [59*512]
static const size_t OFF_WHB  = OFF_WGH + 120832;           // WhB bf16 [64*512]
static const size_t OFF_WFR  = OFF_WHB + 65536;            // WfrT f32 [59*59]
static const size_t OFF_BETA = OFF_WFR + 14080;            // beta f32 [B*T*V] = 23.2 MB

// ------------------- init: transposes / packing -------------------
__global__ void init_k(const float* __restrict__ W_gh, const float* __restrict__ W_hist,
                       const float* __restrict__ W_fr,
                       const float* __restrict__ W_ih, const float* __restrict__ W_hh,
                       float* __restrict__ WghT, unsigned short* __restrict__ WhB,
                       float* __restrict__ WfrT,
                       unsigned short* __restrict__ WgT, unsigned short* __restrict__ A_buf)
{
  int tid = blockIdx.x*blockDim.x + threadIdx.x;
  int nt  = gridDim.x*blockDim.x;
  for (int i = tid; i < V_*H_; i += nt){ int v = i >> 9, j = i & 511; WghT[i] = W_gh[j*V_ + v]; }
  for (int i = tid; i < 64*H_; i += nt){ int n = i >> 9; WhB[i] = (n < V_) ? f2bf(W_hist[i]) : (unsigned short)0; }
  for (int i = tid; i < V_*V_; i += nt){ int u = i / V_, v = i - u*V_; WfrT[i] = (u==v) ? 0.f : W_fr[v*V_ + u]; }
  for (int i = tid; i < G4_*KP_; i += nt){
    int n = i / KP_, k = i - n*KP_;
    float v = 0.f;
    if (k < 2*V_)      v = W_ih[n*(2*V_) + k];
    else if (k < 630)  v = W_hh[n*H_ + (k-118)];
    WgT[i] = f2bf(v);
  }
  for (int i = tid; i < B_*10; i += nt){ int b = i / 10, p = i - b*10; A_buf[(size_t)b*KP_ + 630 + p] = 0; }
}

// ------------------- beta + loss-den precompute (recurrence-independent) -------------------
__global__ __launch_bounds__(256) void beta_k(
    const float* __restrict__ mk, const float* __restrict__ dl,
    const float* __restrict__ w_gx, const float* __restrict__ b_gx,
    const float* __restrict__ W_wc, const float* __restrict__ b_wc,
    float* __restrict__ beta_pre, float* __restrict__ loss_den)
{
  __shared__ float gx[4][64], mm[4][64];
  const int tid = threadIdx.x;
  const int rw  = tid >> 6, v = tid & 63;
  const int row = blockIdx.x*4 + rw;           // row = b*T + t
  size_t base = (size_t)row * V_;
  float m = 0.f, g = 0.f;
  if (v < V_){
    float d = dl[base+v];
    m = mk[base+v];
    g = expf(-fmaxf(d*w_gx[v]+b_gx[v], 0.f));
  }
  gx[rw][v] = g; mm[rw][v] = m;
  __syncthreads();
  if (v < V_){
    float bt = b_wc[v];
    const float* wr = W_wc + (size_t)v*(2*V_);
    for (int u = 0; u < V_; ++u)
      bt += gx[rw][u]*wr[u] + mm[rw][u]*wr[V_+u];
    beta_pre[base+v] = bt;
  }
  float s = m;
#pragma unroll
  for (int off=32; off; off>>=1) s += __shfl_down(s, off);
  if (v == 0){
    int t = row % T_;
    atomicAdd(&loss_den[t], s);
  }
}

// ------------------- device-scope grid barrier (all 256 blocks co-resident) -------------------
__device__ __forceinline__ void grid_bar(unsigned int* cnt, unsigned int target){
  __syncthreads();
  if (threadIdx.x == 0){
    __threadfence();   // release: publish this block's global writes (wb/inv across XCD L2s)
    __hip_atomic_fetch_add(cnt, 1u, __ATOMIC_RELEASE, __HIP_MEMORY_SCOPE_AGENT);
    while (__hip_atomic_load(cnt, __ATOMIC_RELAXED, __HIP_MEMORY_SCOPE_AGENT) < target)
      __builtin_amdgcn_s_sleep(1);
    __threadfence();   // acquire: invalidate stale L1/L2 lines before re-reading A/h
  }
  __syncthreads();
}

// ------------------- persistent fused kernel: whole T loop, 2 barriers/step -------------------
__global__ __launch_bounds__(512) void fused(
    const float* __restrict__ x, const float* __restrict__ mk, const float* __restrict__ dl,
    const float* __restrict__ b_gh, const float* __restrict__ b_hist, const float* __restrict__ b_fr,
    const float* __restrict__ WghT, const unsigned short* __restrict__ WhB,
    const float* __restrict__ WfrT, const float* __restrict__ beta_pre,
    const unsigned short* __restrict__ WgT,
    const float* __restrict__ b_ih, const float* __restrict__ b_hh,
    float* h_ws, unsigned short* A_buf, unsigned int* bar_cnt,
    float* loss_num, const float* __restrict__ loss_den,
    float* __restrict__ out_ximp, float* __restrict__ out_hid, float* __restrict__ out_loss)
{
  __shared__ union {
    struct {
      float d_s[512], m_s[512], x_s[512], xh_s[512], xr_s[512];
      unsigned short hA[16*520];
      float red[8];
    } p1;
    struct { uint4 sA[1024]; uint4 sB[1024]; } p2;   // xor-swizzled bf16 tiles
  } sm;

  const int tid  = threadIdx.x;
  const int blk  = blockIdx.x;
  const int r1   = blk * 8;            // phase-1 rows
  const int r0   = (blk & 15) * 128;   // phase-2 rows
  const int j0   = (blk >> 4) * 32;    // phase-2 hidden units
  const int wid  = tid >> 6;
  const int lane = tid & 63;
  const int col  = lane & 15;
  const int quad = lane >> 4;
  const int rg   = wid >> 1;
  const int uh   = wid & 1;

  // LSTM biases for this thread's fixed unit (t-invariant)
  const int u2 = j0 + uh*16 + col;
  const float bi  = b_ih[u2]      + b_hh[u2];
  const float bfg = b_ih[H_+u2]   + b_hh[H_+u2];
  const float bgg = b_ih[2*H_+u2] + b_hh[2*H_+u2];
  const float bog = b_ih[3*H_+u2] + b_hh[3*H_+u2];
  const float bgj = b_gh[tid];

  // c lives in registers for the whole sequence (thread owns fixed (b,u) pairs)
  float creg[2][4];
#pragma unroll
  for (int i=0;i<2;++i)
#pragma unroll
    for (int r=0;r<4;++r) creg[i][r] = 0.f;

  unsigned int tgt = 0;

  for (int t = 0; t < T_; ++t){
    // ================= phase 1 =================
    if (tid < 8*V_){
      int b = tid / V_, v = tid - b*V_;
      size_t g = ((size_t)(r1+b)*T_ + t)*V_ + v;
      sm.p1.d_s[b*64+v] = dl[g];
      sm.p1.m_s[b*64+v] = mk[g];
      sm.p1.x_s[b*64+v] = x[g];
    }
    __syncthreads();

    // gamma_h and decayed h~ ; thread = hidden unit j
    {
      float acc[8];
#pragma unroll
      for (int b=0;b<8;++b) acc[b]=0.f;
      for (int v=0; v<V_; ++v){
        float wv = WghT[v*H_ + tid];
#pragma unroll
        for (int b=0;b<8;++b) acc[b] += sm.p1.d_s[b*64+v]*wv;
      }
#pragma unroll
      for (int b=0;b<8;++b){
        float gh = expf(-fmaxf(acc[b]+bgj, 0.f));
        float hv = h_ws[(size_t)(r1+b)*H_ + tid] * gh;
        unsigned short hb = f2bf(hv);
        sm.p1.hA[b*520 + tid] = hb;                 // rows 8..15 garbage: only D rows 0..7 used
        A_buf[(size_t)(r1+b)*KP_ + 118 + tid] = hb;
      }
    }
    __syncthreads();

    if (tid < 256){
      // waves 0..3: x_h = h~ @ W_hist^T via MFMA
      f32x4 acc = (f32x4)(0.f);
      const unsigned short* wb = WhB + (size_t)(wid*16 + col)*H_;
#pragma unroll
      for (int kk = 0; kk < 16; ++kk){
        bf16x8 a  = *reinterpret_cast<const bf16x8*>(&sm.p1.hA[col*520 + kk*32 + quad*8]);
        bf16x8 bb = *reinterpret_cast<const bf16x8*>(wb + kk*32 + quad*8);
        acc = __builtin_amdgcn_mfma_f32_16x16x32_bf16(a, bb, acc, 0, 0, 0);
      }
      if (quad < 2){
        int v = wid*16 + col;
        float bh = (v < V_) ? b_hist[v] : 0.f;
#pragma unroll
        for (int r=0;r<4;++r) sm.p1.xh_s[(quad*4+r)*64 + v] = acc[r] + bh;
      }
    } else {
      // waves 4..7: mask column of A
      for (int i = tid - 256; i < 512; i += 256){
        int b = i >> 6, v = i & 63;
        if (v < V_) A_buf[(size_t)(r1+b)*KP_ + V_ + v] = f2bf(sm.p1.m_s[b*64+v]);
      }
    }
    __syncthreads();

    // x_r
    {
      int b = wid, v = lane;
      if (v < V_){
        float mm2 = sm.p1.m_s[b*64+v];
        sm.p1.xr_s[b*64+v] = mm2*sm.p1.x_s[b*64+v] + (1.f-mm2)*sm.p1.xh_s[b*64+v];
      }
    }
    __syncthreads();

    // xu (feature regression), precomputed beta, x_comb, x_imp, loss num
    float num = 0.f;
    {
      int b = wid, v = lane;
      if (v < V_){
        float xu = b_fr[v];
        for (int u=0; u<V_; ++u) xu += sm.p1.xr_s[b*64+u]*WfrT[u*V_+v];
        float bt = beta_pre[((size_t)(r1+b)*T_ + t)*V_ + v];
        float xh = sm.p1.xh_s[b*64+v];
        float xc = bt*xu + (1.f-bt)*xh;
        float mm2 = sm.p1.m_s[b*64+v], xx = sm.p1.x_s[b*64+v];
        num = fabsf(xx - xc)*mm2;
        float xi = mm2*xx + (1.f-mm2)*xc;
        out_ximp[((size_t)(r1+b)*T_ + t)*V_ + v] = xi;
        A_buf[(size_t)(r1+b)*KP_ + v] = f2bf(xi);
      }
    }
#pragma unroll
    for (int off=32; off; off>>=1) num += __shfl_down(num, off);
    if (lane == 0) sm.p1.red[wid] = num;
    __syncthreads();
    if (tid == 0){
      float n = 0.f;
#pragma unroll
      for (int i=0;i<8;++i) n += sm.p1.red[i];
      atomicAdd(&loss_num[t], n);
    }

    grid_bar(bar_cnt, tgt += NBLK_);   // A(t) complete, visible everywhere

    // ================= phase 2: gates GEMM + LSTM =================
    f32x4 acc2[2][4];
#pragma unroll
    for (int i=0;i<2;++i)
#pragma unroll
      for (int g=0;g<4;++g) acc2[i][g] = (f32x4)(0.f);

    for (int s = 0; s < 10; ++s){      // K = 640 in 10 stages of 64
#pragma unroll
      for (int p=0; p<2; ++p){
        int idx = p*512 + tid;
        int r = idx >> 3, c = idx & 7;
        sm.p2.sA[r*8 + (c ^ (r&7))] = *reinterpret_cast<const uint4*>(A_buf + (size_t)(r0+r)*KP_ + s*64 + c*8);
        int ng = ((r>>5)<<9) + j0 + (r&31);
        sm.p2.sB[r*8 + (c ^ (r&7))] = *reinterpret_cast<const uint4*>(WgT + (size_t)ng*KP_ + s*64 + c*8);
      }
      __syncthreads();
#pragma unroll
      for (int kk=0; kk<2; ++kk){
        bf16x8 af[2], bfr[4];
#pragma unroll
        for (int mf=0; mf<2; ++mf){
          int r = rg*32 + mf*16 + col;
          af[mf] = *reinterpret_cast<const bf16x8*>(&sm.p2.sA[r*8 + ((kk*4+quad) ^ (r&7))]);
        }
#pragma unroll
        for (int g=0; g<4; ++g){
          int r = g*32 + uh*16 + col;
          bfr[g] = *reinterpret_cast<const bf16x8*>(&sm.p2.sB[r*8 + ((kk*4+quad) ^ (r&7))]);
        }
#pragma unroll
        for (int mf=0; mf<2; ++mf)
#pragma unroll
          for (int g=0; g<4; ++g)
            acc2[mf][g] = __builtin_amdgcn_mfma_f32_16x16x32_bf16(af[mf], bfr[g], acc2[mf][g], 0, 0, 0);
      }
      __syncthreads();
    }

    // LSTM epilogue: c in registers, h to global
    {
#pragma unroll
      for (int mf=0; mf<2; ++mf){
#pragma unroll
        for (int r=0; r<4; ++r){
          int b = r0 + rg*32 + mf*16 + quad*4 + r;
          float gi = acc2[mf][0][r] + bi;
          float gf = acc2[mf][1][r] + bfg;
          float gg = acc2[mf][2][r] + bgg;
          float go = acc2[mf][3][r] + bog;
          float cn = sigf(gf)*creg[mf][r] + sigf(gi)*tanhf(gg);
          float hn = sigf(go)*tanhf(cn);
          creg[mf][r] = cn;
          h_ws[(size_t)b*H_ + u2] = hn;
          out_hid[((size_t)b*T_ + t)*H_ + u2] = hn;
        }
      }
    }

    grid_bar(bar_cnt, tgt += NBLK_);   // h(t) complete before next phase 1
  }

  // final loss
  if (blk == 0 && tid < 64){
    float v = 0.f;
    if (tid < T_) v = loss_num[tid]/(loss_den[tid] + 1e-5f);
#pragma unroll
    for (int off=32; off; off>>=1) v += __shfl_down(v, off);
    if (tid == 0) *out_loss = v;
  }
}

extern "C" void kernel_launch(void* const* d_in, const int* in_sizes, int n_in,
                              void* d_out, int out_size, void* d_ws, size_t ws_size,
                              hipStream_t stream)
{
  const float* x      = (const float*)d_in[0];
  const float* mk     = (const float*)d_in[1];
  const float* dl     = (const float*)d_in[2];
  const float* W_gh   = (const float*)d_in[3];
  const float* b_gh   = (const float*)d_in[4];
  const float* w_gx   = (const float*)d_in[5];
  const float* b_gx   = (const float*)d_in[6];
  const float* W_hist = (const float*)d_in[7];
  const float* b_hist = (const float*)d_in[8];
  const float* W_fr   = (const float*)d_in[9];
  const float* b_fr   = (const float*)d_in[10];
  const float* W_wc   = (const float*)d_in[11];
  const float* b_wc   = (const float*)d_in[12];
  const float* W_ih   = (const float*)d_in[13];
  const float* W_hh   = (const float*)d_in[14];
  const float* b_ih   = (const float*)d_in[15];
  const float* b_hh   = (const float*)d_in[16];

  char* ws = (char*)d_ws;
  float*          h_ws   = (float*)(ws + OFF_H);
  float*          lnum   = (float*)(ws + OFF_LN);
  float*          lden   = (float*)(ws + OFF_LD);
  unsigned int*   cnt    = (unsigned int*)(ws + OFF_CNT);
  unsigned short* A_buf  = (unsigned short*)(ws + OFF_A);
  unsigned short* WgT    = (unsigned short*)(ws + OFF_WGT);
  float*          WghT   = (float*)(ws + OFF_WGH);
  unsigned short* WhB    = (unsigned short*)(ws + OFF_WHB);
  float*          WfrT   = (float*)(ws + OFF_WFR);
  float*          beta   = (float*)(ws + OFF_BETA);

  float* out      = (float*)d_out;
  float* out_ximp = out;                                   // [B,T,V]
  float* out_loss = out + (size_t)B_*T_*V_;                // scalar
  float* out_hid  = out + (size_t)B_*T_*V_ + 1;            // [B,T,H]

  hipMemsetAsync(d_ws, 0, MEMSET_BYTES, stream);           // h, loss accumulators, barrier counter
  init_k<<<1024, 256, 0, stream>>>(W_gh, W_hist, W_fr, W_ih, W_hh,
                                   WghT, WhB, WfrT, WgT, A_buf);
  beta_k<<<(B_*T_)/4, 256, 0, stream>>>(mk, dl, w_gx, b_gx, W_wc, b_wc, beta, lden);
  fused<<<NBLK_, 512, 0, stream>>>(x, mk, dl, b_gh, b_hist, b_fr,
                                   WghT, WhB, WfrT, beta, WgT, b_ih, b_hh,
                                   h_ws, A_buf, cnt, lnum, lden,
                                   out_ximp, out_hid, out_loss);
}